// Round 1
// baseline (3599.997 us; speedup 1.0000x reference)
//
#include <hip/hip_runtime.h>
#include <cmath>

#define TT 256
#define BB 512
#define DD 128
#define HH 128
#define NCOL 528   // 4*H + 16 quantum-angle cols
#define KK 256     // D + H
#define RPW 4      // batch rows per workgroup
#define NWG (BB / RPW)   // 128
#define NTHR 1024

// Pack the 8 weight matrices into W4[k4][col][4] (float4 per (col,k-group)) and bcat[528].
// col 0-127: f, 128-255: i, 256-383: g, 384-511: o, 512-515: fq, 516-519: iq, 520-523: gq, 524-527: oq
__global__ __launch_bounds__(256) void pack_weights(
    const float* __restrict__ Wf, const float* __restrict__ bf,
    const float* __restrict__ Wfq, const float* __restrict__ bfq,
    const float* __restrict__ Wi, const float* __restrict__ bi,
    const float* __restrict__ Wiq, const float* __restrict__ biq,
    const float* __restrict__ Wg, const float* __restrict__ bg,
    const float* __restrict__ Wgq, const float* __restrict__ bgq,
    const float* __restrict__ Wo, const float* __restrict__ bo,
    const float* __restrict__ Woq, const float* __restrict__ boq,
    float4* __restrict__ W4, float* __restrict__ bcat)
{
    int idx = blockIdx.x * blockDim.x + threadIdx.x;
    int total = NCOL * (KK / 4);
    if (idx < total) {
        int k4 = idx / NCOL;
        int c  = idx - k4 * NCOL;
        const float* srcW; int cl;
        if      (c < 128) { srcW = Wf;  cl = c; }
        else if (c < 256) { srcW = Wi;  cl = c - 128; }
        else if (c < 384) { srcW = Wg;  cl = c - 256; }
        else if (c < 512) { srcW = Wo;  cl = c - 384; }
        else if (c < 516) { srcW = Wfq; cl = c - 512; }
        else if (c < 520) { srcW = Wiq; cl = c - 516; }
        else if (c < 524) { srcW = Wgq; cl = c - 520; }
        else              { srcW = Woq; cl = c - 524; }
        const float* p = srcW + (size_t)cl * KK + k4 * 4;
        W4[(size_t)k4 * NCOL + c] = make_float4(p[0], p[1], p[2], p[3]);
    }
    if (idx < NCOL) {
        int c = idx; float b;
        if      (c < 128) b = bf[c];
        else if (c < 256) b = bi[c - 128];
        else if (c < 384) b = bg[c - 256];
        else if (c < 512) b = bo[c - 384];
        else if (c < 516) b = bfq[c - 512];
        else if (c < 520) b = biq[c - 516];
        else if (c < 524) b = bgq[c - 520];
        else              b = boq[c - 524];
        bcat[c] = b;
    }
}

__device__ __forceinline__ float sigm(float x) {
    return 1.0f / (1.0f + __expf(-x));
}

// Persistent kernel: each WG owns RPW batch rows for all TT steps. No inter-WG deps.
__global__ __launch_bounds__(NTHR, 4) void qlstm_main(
    const float* __restrict__ X, const float* __restrict__ hx0, const float* __restrict__ cx0,
    const float4* __restrict__ W4, const float* __restrict__ bcat_g,
    const float* __restrict__ Wq, const float* __restrict__ bq,
    const float* __restrict__ thf, const float* __restrict__ thi,
    const float* __restrict__ thg, const float* __restrict__ tho,
    float* __restrict__ out)
{
    __shared__ __align__(16) float comb[RPW][KK];   // [r][0:128)=x_t, [128:256)=hx
    __shared__ float S[RPW][NCOL];
    __shared__ float EZ[RPW][4][4];
    __shared__ float cxL[RPW][HH];
    __shared__ float WqT[4][HH];
    __shared__ float bqL[HH];
    __shared__ float bcat[NCOL];

    const int tid  = threadIdx.x;
    const int row0 = blockIdx.x * RPW;

    // ---- one-time init ----
    if (tid < 512) {
        int r = tid >> 7, h = tid & 127;
        comb[r][DD + h] = hx0[(size_t)(row0 + r) * HH + h];
        cxL[r][h]       = cx0[(size_t)(row0 + r) * HH + h];
    }
    if (tid < HH) {
        bqL[tid]    = bq[tid];
        WqT[0][tid] = Wq[tid * 4 + 0];
        WqT[1][tid] = Wq[tid * 4 + 1];
        WqT[2][tid] = Wq[tid * 4 + 2];
        WqT[3][tid] = Wq[tid * 4 + 3];
    }
    if (tid < NCOL) bcat[tid] = bcat_g[tid];

    // hoist theta-layer RX constants (time-invariant)
    float cs2[4], sn2[4];
    {
        int gate = (tid >> 4) & 3;
        const float* thp = (gate == 0) ? thf : (gate == 1) ? thi : (gate == 2) ? thg : tho;
        #pragma unroll
        for (int w = 0; w < 4; ++w)
            sincosf(0.5f * thp[w], &sn2[w], &cs2[w]);
    }
    __syncthreads();

    // GEMM task (col, row-base): dot(comb[rb..rb+1][:], Wcat[col][:]) + bias
    auto gemm_task = [&](int col, int rb) {
        const float4* wp = W4 + col;
        const float4* a0 = reinterpret_cast<const float4*>(&comb[rb][0]);
        const float4* a1 = reinterpret_cast<const float4*>(&comb[rb + 1][0]);
        float acc0a = 0.f, acc0b = 0.f, acc1a = 0.f, acc1b = 0.f;
        #pragma unroll 8
        for (int k4 = 0; k4 < KK / 4; k4 += 2) {
            float4 w0 = wp[(size_t)k4 * NCOL];
            float4 w1 = wp[(size_t)(k4 + 1) * NCOL];
            float4 p0 = a0[k4], q0 = a0[k4 + 1];
            float4 p1 = a1[k4], q1 = a1[k4 + 1];
            acc0a = fmaf(w0.x, p0.x, fmaf(w0.y, p0.y, fmaf(w0.z, p0.z, fmaf(w0.w, p0.w, acc0a))));
            acc0b = fmaf(w1.x, q0.x, fmaf(w1.y, q0.y, fmaf(w1.z, q0.z, fmaf(w1.w, q0.w, acc0b))));
            acc1a = fmaf(w0.x, p1.x, fmaf(w0.y, p1.y, fmaf(w0.z, p1.z, fmaf(w0.w, p1.w, acc1a))));
            acc1b = fmaf(w1.x, q1.x, fmaf(w1.y, q1.y, fmaf(w1.z, q1.z, fmaf(w1.w, q1.w, acc1b))));
        }
        float b = bcat[col];
        S[rb][col]     = acc0a + acc0b + b;
        S[rb + 1][col] = acc1a + acc1b + b;
    };

    for (int t = 0; t < TT; ++t) {
        // load x_t rows for this WG
        if (tid < 512) {
            int r = tid >> 7, d = tid & 127;
            comb[r][d] = X[((size_t)t * BB + row0 + r) * DD + d];
        }
        __syncthreads();

        // ---- GEMM: 528 cols x 4 rows ----
        {
            int col = (tid < NCOL) ? tid : tid - NCOL;
            int rb  = (tid < NCOL) ? 0 : 2;
            gemm_task(col, rb);
            if (tid < 32) gemm_task(496 + tid, 2);  // remaining 32 (col,rp=1) tasks
        }
        __syncthreads();

        // ---- quantum sims: 16 sims (4 rows x 4 gates) x 16 lanes (one amplitude each) ----
        if (tid < 256) {
            int m    = tid & 15;       // amplitude index; wire w <-> bit (3-w)
            int sim  = tid >> 4;
            int r    = sim >> 2, gate = sim & 3;
            float re = (m == 0) ? 1.f : 0.f;
            float im = 0.f;
            // RX(angle) layer
            #pragma unroll
            for (int w = 0; w < 4; ++w) {
                float sn, cs;
                __sincosf(0.5f * S[r][512 + gate * 4 + w], &sn, &cs);
                int st = 8 >> w;
                float pre = __shfl_xor(re, st, 64);
                float pim = __shfl_xor(im, st, 64);
                float nre = fmaf(cs, re,  sn * pim);
                float nim = fmaf(cs, im, -sn * pre);
                re = nre; im = nim;
            }
            // CNOT chain (ctrl w, target w+1)
            #pragma unroll
            for (int ctrl = 0; ctrl < 3; ++ctrl) {
                int cmask = 8 >> ctrl;
                int tmask = 4 >> ctrl;
                float pre = __shfl_xor(re, tmask, 64);
                float pim = __shfl_xor(im, tmask, 64);
                if (m & cmask) { re = pre; im = pim; }
            }
            // RX(theta) layer (hoisted constants)
            #pragma unroll
            for (int w = 0; w < 4; ++w) {
                int st = 8 >> w;
                float pre = __shfl_xor(re, st, 64);
                float pim = __shfl_xor(im, st, 64);
                float nre = fmaf(cs2[w], re,  sn2[w] * pim);
                float nim = fmaf(cs2[w], im, -sn2[w] * pre);
                re = nre; im = nim;
            }
            // <Z_w> per wire
            float prob = re * re + im * im;
            #pragma unroll
            for (int w = 0; w < 4; ++w) {
                float v = (m & (8 >> w)) ? -prob : prob;
                v += __shfl_xor(v, 1, 64);
                v += __shfl_xor(v, 2, 64);
                v += __shfl_xor(v, 4, 64);
                v += __shfl_xor(v, 8, 64);
                if (m == w) EZ[r][gate][w] = v;
            }
        }
        __syncthreads();

        // ---- cell update ----
        if (tid < 512) {
            int r = tid >> 7, h = tid & 127;
            float b  = bqL[h];
            float w0 = WqT[0][h], w1 = WqT[1][h], w2 = WqT[2][h], w3 = WqT[3][h];
            float qf = fmaf(EZ[r][0][0], w0, fmaf(EZ[r][0][1], w1, fmaf(EZ[r][0][2], w2, fmaf(EZ[r][0][3], w3, b))));
            float qi = fmaf(EZ[r][1][0], w0, fmaf(EZ[r][1][1], w1, fmaf(EZ[r][1][2], w2, fmaf(EZ[r][1][3], w3, b))));
            float qg = fmaf(EZ[r][2][0], w0, fmaf(EZ[r][2][1], w1, fmaf(EZ[r][2][2], w2, fmaf(EZ[r][2][3], w3, b))));
            float qo = fmaf(EZ[r][3][0], w0, fmaf(EZ[r][3][1], w1, fmaf(EZ[r][3][2], w2, fmaf(EZ[r][3][3], w3, b))));
            float f  = sigm(S[r][h])           + sigm(qf);
            float ii = sigm(S[r][HH + h])      + sigm(qi);
            float gg = tanhf(S[r][2 * HH + h]) + tanhf(qg);
            float oo = sigm(S[r][3 * HH + h])  + sigm(qo);
            float cn = fmaf(f, cxL[r][h], ii * gg);
            cxL[r][h] = cn;
            float hn = oo * tanhf(cn);
            comb[r][DD + h] = hn;
            out[((size_t)t * BB + row0 + r) * HH + h] = hn;
        }
        __syncthreads();
    }

    // ---- final (hxT, cxT) ----
    if (tid < 512) {
        int r = tid >> 7, h = tid & 127;
        size_t base = (size_t)TT * BB * HH;
        out[base + (size_t)(row0 + r) * HH + h]                    = comb[r][DD + h];
        out[base + (size_t)BB * HH + (size_t)(row0 + r) * HH + h]  = cxL[r][h];
    }
}

extern "C" void kernel_launch(void* const* d_in, const int* in_sizes, int n_in,
                              void* d_out, int out_size, void* d_ws, size_t ws_size,
                              hipStream_t stream) {
    const float* X   = (const float*)d_in[0];
    const float* hx0 = (const float*)d_in[1];
    const float* cx0 = (const float*)d_in[2];
    const float* Wf  = (const float*)d_in[3];
    const float* bf  = (const float*)d_in[4];
    const float* Wfq = (const float*)d_in[5];
    const float* bfq = (const float*)d_in[6];
    const float* thf = (const float*)d_in[7];
    const float* Wi  = (const float*)d_in[8];
    const float* bi  = (const float*)d_in[9];
    const float* Wiq = (const float*)d_in[10];
    const float* biq = (const float*)d_in[11];
    const float* thi = (const float*)d_in[12];
    const float* Wg  = (const float*)d_in[13];
    const float* bg  = (const float*)d_in[14];
    const float* Wgq = (const float*)d_in[15];
    const float* bgq = (const float*)d_in[16];
    const float* thg = (const float*)d_in[17];
    const float* Wo  = (const float*)d_in[18];
    const float* bo  = (const float*)d_in[19];
    const float* Woq = (const float*)d_in[20];
    const float* boq = (const float*)d_in[21];
    const float* tho = (const float*)d_in[22];
    const float* Wq  = (const float*)d_in[23];
    const float* bq  = (const float*)d_in[24];

    float4* W4   = (float4*)d_ws;
    float*  bcat = (float*)((char*)d_ws + (size_t)NCOL * (KK / 4) * sizeof(float4));

    int total = NCOL * (KK / 4);
    pack_weights<<<(total + 255) / 256, 256, 0, stream>>>(
        Wf, bf, Wfq, bfq, Wi, bi, Wiq, biq, Wg, bg, Wgq, bgq, Wo, bo, Woq, boq, W4, bcat);

    qlstm_main<<<NWG, NTHR, 0, stream>>>(
        X, hx0, cx0, W4, bcat, Wq, bq, thf, thi, thg, tho, (float*)d_out);
}

// Round 2
// 1336.273 us; speedup vs baseline: 2.6941x; 2.6941x over previous
//
#include <hip/hip_runtime.h>
#include <cmath>

#define TT 256
#define BB 512
#define DD 128
#define HH 128
#define NCOL 528   // 4*H + 16 quantum-angle cols
#define KK 256
#define NCPAD 576  // 9 * 64

// ---------------- weight pack: Wxp[528][128], Whp[528][128], bcat[576] ----------------
__global__ __launch_bounds__(256) void pack_weights(
    const float* __restrict__ Wf, const float* __restrict__ bf,
    const float* __restrict__ Wfq, const float* __restrict__ bfq,
    const float* __restrict__ Wi, const float* __restrict__ bi,
    const float* __restrict__ Wiq, const float* __restrict__ biq,
    const float* __restrict__ Wg, const float* __restrict__ bg,
    const float* __restrict__ Wgq, const float* __restrict__ bgq,
    const float* __restrict__ Wo, const float* __restrict__ bo,
    const float* __restrict__ Woq, const float* __restrict__ boq,
    float* __restrict__ Wxp, float* __restrict__ Whp, float* __restrict__ bcat)
{
    int idx = blockIdx.x * blockDim.x + threadIdx.x;
    if (idx < NCOL * KK) {
        int c = idx >> 8, k = idx & 255;
        const float* srcW; int cl;
        if (c < 512) { int g = c >> 7; cl = c & 127;
            srcW = (g == 0) ? Wf : (g == 1) ? Wi : (g == 2) ? Wg : Wo; }
        else { int g = (c - 512) >> 2; cl = (c - 512) & 3;
            srcW = (g == 0) ? Wfq : (g == 1) ? Wiq : (g == 2) ? Wgq : Woq; }
        float v = srcW[(size_t)cl * KK + k];
        if (k < 128) Wxp[(size_t)c * 128 + k] = v;
        else         Whp[(size_t)c * 128 + (k - 128)] = v;
    }
    if (idx < NCPAD) {
        float b = 0.f;
        int c = idx;
        if (c < 512) { int g = c >> 7; int cl = c & 127;
            b = (g == 0) ? bf[cl] : (g == 1) ? bi[cl] : (g == 2) ? bg[cl] : bo[cl]; }
        else if (c < NCOL) { int g = (c - 512) >> 2; int cl = (c - 512) & 3;
            b = (g == 0) ? bfq[cl] : (g == 1) ? biq[cl] : (g == 2) ? bgq[cl] : boq[cl]; }
        bcat[c] = b;
    }
}

// ---------------- phase 1: Zx = X @ Wx^T + bcat  (M x 528, K=128) ----------------
#define P1_BM 128
#define P1_BN 64
__global__ __launch_bounds__(256, 3) void xgemm(
    const float* __restrict__ X, const float* __restrict__ Wxp,
    const float* __restrict__ bcat, float* __restrict__ Zx)
{
    __shared__ float At[64][P1_BM];  // [k][m], no pad (stride 128/64 benign for these patterns)
    __shared__ float Bt[64][P1_BN];  // [k][n]
    const int tid = threadIdx.x;
    const int m0 = blockIdx.x * P1_BM;
    const int c0 = blockIdx.y * P1_BN;
    const int tm = tid >> 4;   // 0..15 -> rows tm*8..
    const int tn = tid & 15;   // 0..15 -> cols tn*4..
    float acc[8][4] = {};

    for (int khf = 0; khf < 2; ++khf) {
        // stage A: 128 rows x 64 k (transposed)
        #pragma unroll
        for (int j = 0; j < 8; ++j) {
            int fidx = tid + 256 * j;            // 0..2047
            int m = fidx >> 4, k4 = (fidx & 15) * 4;
            float4 v = *(const float4*)(X + (size_t)(m0 + m) * 128 + khf * 64 + k4);
            At[k4 + 0][m] = v.x; At[k4 + 1][m] = v.y; At[k4 + 2][m] = v.z; At[k4 + 3][m] = v.w;
        }
        // stage B: 64 cols x 64 k (transposed), zero-fill past 528
        #pragma unroll
        for (int j = 0; j < 4; ++j) {
            int fidx = tid + 256 * j;            // 0..1023
            int c = fidx >> 4, k4 = (fidx & 15) * 4;
            int cg = c0 + c;
            float4 v = make_float4(0.f, 0.f, 0.f, 0.f);
            if (cg < NCOL) v = *(const float4*)(Wxp + (size_t)cg * 128 + khf * 64 + k4);
            Bt[k4 + 0][c] = v.x; Bt[k4 + 1][c] = v.y; Bt[k4 + 2][c] = v.z; Bt[k4 + 3][c] = v.w;
        }
        __syncthreads();
        #pragma unroll 4
        for (int k = 0; k < 64; ++k) {
            float4 a0 = *(const float4*)&At[k][tm * 8];
            float4 a1 = *(const float4*)&At[k][tm * 8 + 4];
            float4 b  = *(const float4*)&Bt[k][tn * 4];
            float ar[8] = {a0.x, a0.y, a0.z, a0.w, a1.x, a1.y, a1.z, a1.w};
            float br[4] = {b.x, b.y, b.z, b.w};
            #pragma unroll
            for (int i = 0; i < 8; ++i)
                #pragma unroll
                for (int j = 0; j < 4; ++j)
                    acc[i][j] = fmaf(ar[i], br[j], acc[i][j]);
        }
        __syncthreads();
    }
    int c = c0 + tn * 4;
    if (c < NCOL) {
        float4 bias = *(const float4*)(bcat + c);
        #pragma unroll
        for (int i = 0; i < 8; ++i) {
            int m = m0 + tm * 8 + i;
            float4 o;
            o.x = acc[i][0] + bias.x; o.y = acc[i][1] + bias.y;
            o.z = acc[i][2] + bias.z; o.w = acc[i][3] + bias.w;
            *(float4*)(Zx + (size_t)m * NCOL + c) = o;
        }
    }
}

// ---------------- phase 2: recurrence, Wh register-resident ----------------
__device__ __forceinline__ float sigm(float x) { return 1.0f / (1.0f + __expf(-x)); }
__device__ __forceinline__ float tanh_f(float x) {
    float e = __expf(2.f * x);
    return 1.f - 2.f / (e + 1.f);
}

__global__ __launch_bounds__(1024, 4) void qlstm_rec(
    const float* __restrict__ Zx,      // [TC][512][528]
    const float* __restrict__ Whp,     // [528][128]
    const float* __restrict__ hx0, const float* __restrict__ cx0,
    float* __restrict__ stateH, float* __restrict__ stateC,
    const float* __restrict__ Wq, const float* __restrict__ bq,
    const float* __restrict__ thf, const float* __restrict__ thi,
    const float* __restrict__ thg, const float* __restrict__ tho,
    float* __restrict__ out, int t0, int TC)
{
    __shared__ __align__(16) float hL[2][HH];
    __shared__ __align__(16) float cxL[2][HH];
    __shared__ float P[2][512][2];
    __shared__ float Pq[2][16][2];
    __shared__ float EZ[2][4][4];
    __shared__ float Whq[16][132];
    __shared__ float WqT[4][HH];
    __shared__ float bqL[HH];

    const int tid  = threadIdx.x;
    const int row0 = blockIdx.x * 2;
    const int col  = tid >> 1;       // 0..511
    const int kh   = tid & 1;        // k-half

    // weights into registers: 16 float4 = 64 floats per thread, whole Wh per WG
    float4 w4[16];
    {
        const float4* wp = (const float4*)(Whp + ((size_t)col * 128 + kh * 64));
        #pragma unroll
        for (int j = 0; j < 16; ++j) w4[j] = wp[j];
    }
    if (tid < 512) {
        #pragma unroll
        for (int j = 0; j < 4; ++j) {
            int idx = tid * 4 + j;   // 0..2047
            Whq[idx >> 7][idx & 127] = Whp[(size_t)(512 + (idx >> 7)) * 128 + (idx & 127)];
        }
    }
    if (tid < HH) {
        bqL[tid] = bq[tid];
        WqT[0][tid] = Wq[tid * 4 + 0]; WqT[1][tid] = Wq[tid * 4 + 1];
        WqT[2][tid] = Wq[tid * 4 + 2]; WqT[3][tid] = Wq[tid * 4 + 3];
    }
    if (tid < 256) {
        int r = tid >> 7, h = tid & 127;
        const float* hs = (t0 == 0) ? hx0 : stateH;
        const float* cs = (t0 == 0) ? cx0 : stateC;
        hL[r][h]  = hs[(size_t)(row0 + r) * HH + h];
        cxL[r][h] = cs[(size_t)(row0 + r) * HH + h];
    }
    float cs2[4], sn2[4];
    {
        int gate = (tid >> 5) & 3;
        const float* thp = (gate == 0) ? thf : (gate == 1) ? thi : (gate == 2) ? thg : tho;
        #pragma unroll
        for (int w = 0; w < 4; ++w) { float s, c; sincosf(0.5f * thp[w], &s, &c); sn2[w] = s; cs2[w] = c; }
    }
    __syncthreads();

    for (int tc = 0; tc < TC; ++tc) {
        const float* zrow = Zx + ((size_t)tc * BB + row0) * NCOL;
        // prefetch global Zx values used after the barriers (hidden under GEMM)
        float zc0 = 0, zc1 = 0, zc2 = 0, zc3 = 0, zq = 0;
        if (tid < 256) {
            int r = tid >> 7, h = tid & 127;
            const float* zp = zrow + (size_t)r * NCOL + h;
            zc0 = zp[0]; zc1 = zp[128]; zc2 = zp[256]; zc3 = zp[384];
        }
        if (tid < 128 && (tid & 15) < 4) {
            int r = (tid >> 4) & 1, gate = tid >> 5;
            zq = zrow[(size_t)r * NCOL + 512 + gate * 4 + (tid & 15)];
        }
        // main GEMM: partial dot for (col, kh), both rows
        {
            const float4* h0 = (const float4*)&hL[0][kh << 6];
            const float4* h1 = (const float4*)&hL[1][kh << 6];
            float s0a = 0, s0b = 0, s1a = 0, s1b = 0;
            #pragma unroll
            for (int j = 0; j < 16; j += 2) {
                float4 x0 = h0[j], x1 = h0[j + 1];
                float4 y0 = h1[j], y1 = h1[j + 1];
                float4 u = w4[j], v = w4[j + 1];
                s0a = fmaf(u.x, x0.x, fmaf(u.y, x0.y, fmaf(u.z, x0.z, fmaf(u.w, x0.w, s0a))));
                s0b = fmaf(v.x, x1.x, fmaf(v.y, x1.y, fmaf(v.z, x1.z, fmaf(v.w, x1.w, s0b))));
                s1a = fmaf(u.x, y0.x, fmaf(u.y, y0.y, fmaf(u.z, y0.z, fmaf(u.w, y0.w, s1a))));
                s1b = fmaf(v.x, y1.x, fmaf(v.y, y1.y, fmaf(v.z, y1.z, fmaf(v.w, y1.w, s1b))));
            }
            P[0][col][kh] = s0a + s0b;
            P[1][col][kh] = s1a + s1b;
        }
        // q-angle h-dots (64 extra tasks on wave 0, weights from LDS)
        if (tid < 64) {
            int qc = tid >> 2, k2 = (tid >> 1) & 1, r2 = tid & 1;
            const float* wq_ = &Whq[qc][k2 * 64];
            const float* hh  = &hL[r2][k2 * 64];
            float a = 0, b2 = 0;
            #pragma unroll
            for (int j = 0; j < 64; j += 2) { a = fmaf(wq_[j], hh[j], a); b2 = fmaf(wq_[j + 1], hh[j + 1], b2); }
            Pq[r2][qc][k2] = a + b2;
        }
        __syncthreads();
        // quantum sims: 8 sims x 16 lanes
        if (tid < 128) {
            int m = tid & 15, lane = tid & 63;
            int r = (tid >> 4) & 1, gate = tid >> 5;
            float re = (m == 0) ? 1.f : 0.f, im = 0.f;
            #pragma unroll
            for (int w = 0; w < 4; ++w) {
                float zw = __shfl(zq, (lane & 48) + w, 64);
                int qc = gate * 4 + w;
                float ang = zw + Pq[r][qc][0] + Pq[r][qc][1];
                float sn, cs; __sincosf(0.5f * ang, &sn, &cs);
                int st = 8 >> w;
                float pre = __shfl_xor(re, st, 64);
                float pim = __shfl_xor(im, st, 64);
                float nre = fmaf(cs, re,  sn * pim);
                float nim = fmaf(cs, im, -sn * pre);
                re = nre; im = nim;
            }
            #pragma unroll
            for (int ctrl = 0; ctrl < 3; ++ctrl) {
                int cmask = 8 >> ctrl, tmask = 4 >> ctrl;
                float pre = __shfl_xor(re, tmask, 64);
                float pim = __shfl_xor(im, tmask, 64);
                if (m & cmask) { re = pre; im = pim; }
            }
            #pragma unroll
            for (int w = 0; w < 4; ++w) {
                int st = 8 >> w;
                float pre = __shfl_xor(re, st, 64);
                float pim = __shfl_xor(im, st, 64);
                float nre = fmaf(cs2[w], re,  sn2[w] * pim);
                float nim = fmaf(cs2[w], im, -sn2[w] * pre);
                re = nre; im = nim;
            }
            float prob = re * re + im * im;
            #pragma unroll
            for (int w = 0; w < 4; ++w) {
                float v2 = (m & (8 >> w)) ? -prob : prob;
                v2 += __shfl_xor(v2, 1, 64);
                v2 += __shfl_xor(v2, 2, 64);
                v2 += __shfl_xor(v2, 4, 64);
                v2 += __shfl_xor(v2, 8, 64);
                if (m == w) EZ[r][gate][w] = v2;
            }
        }
        __syncthreads();
        // cell update
        if (tid < 256) {
            int r = tid >> 7, h = tid & 127;
            float pf  = zc0 + P[r][h][0]       + P[r][h][1];
            float pi_ = zc1 + P[r][128 + h][0] + P[r][128 + h][1];
            float pg  = zc2 + P[r][256 + h][0] + P[r][256 + h][1];
            float po  = zc3 + P[r][384 + h][0] + P[r][384 + h][1];
            float w0 = WqT[0][h], w1 = WqT[1][h], w2 = WqT[2][h], w3 = WqT[3][h];
            float bb = bqL[h];
            float qf = fmaf(EZ[r][0][0], w0, fmaf(EZ[r][0][1], w1, fmaf(EZ[r][0][2], w2, fmaf(EZ[r][0][3], w3, bb))));
            float qi = fmaf(EZ[r][1][0], w0, fmaf(EZ[r][1][1], w1, fmaf(EZ[r][1][2], w2, fmaf(EZ[r][1][3], w3, bb))));
            float qg = fmaf(EZ[r][2][0], w0, fmaf(EZ[r][2][1], w1, fmaf(EZ[r][2][2], w2, fmaf(EZ[r][2][3], w3, bb))));
            float qo = fmaf(EZ[r][3][0], w0, fmaf(EZ[r][3][1], w1, fmaf(EZ[r][3][2], w2, fmaf(EZ[r][3][3], w3, bb))));
            float f  = sigm(pf)   + sigm(qf);
            float ii = sigm(pi_)  + sigm(qi);
            float gg = tanh_f(pg) + tanh_f(qg);
            float oo = sigm(po)   + sigm(qo);
            float cn = fmaf(f, cxL[r][h], ii * gg);
            cxL[r][h] = cn;
            float hn = oo * tanh_f(cn);
            hL[r][h] = hn;
            out[((size_t)(t0 + tc) * BB + row0 + r) * HH + h] = hn;
        }
        __syncthreads();
    }

    if (tid < 256) {
        int r = tid >> 7, h = tid & 127;
        stateH[(size_t)(row0 + r) * HH + h] = hL[r][h];
        stateC[(size_t)(row0 + r) * HH + h] = cxL[r][h];
        if (t0 + TC == TT) {
            size_t base = (size_t)TT * BB * HH;
            out[base + (size_t)(row0 + r) * HH + h]                   = hL[r][h];
            out[base + (size_t)BB * HH + (size_t)(row0 + r) * HH + h] = cxL[r][h];
        }
    }
}

extern "C" void kernel_launch(void* const* d_in, const int* in_sizes, int n_in,
                              void* d_out, int out_size, void* d_ws, size_t ws_size,
                              hipStream_t stream) {
    const float* X   = (const float*)d_in[0];
    const float* hx0 = (const float*)d_in[1];
    const float* cx0 = (const float*)d_in[2];
    const float* Wf  = (const float*)d_in[3];
    const float* bf  = (const float*)d_in[4];
    const float* Wfq = (const float*)d_in[5];
    const float* bfq = (const float*)d_in[6];
    const float* thf = (const float*)d_in[7];
    const float* Wi  = (const float*)d_in[8];
    const float* bi  = (const float*)d_in[9];
    const float* Wiq = (const float*)d_in[10];
    const float* biq = (const float*)d_in[11];
    const float* thi = (const float*)d_in[12];
    const float* Wg  = (const float*)d_in[13];
    const float* bg  = (const float*)d_in[14];
    const float* Wgq = (const float*)d_in[15];
    const float* bgq = (const float*)d_in[16];
    const float* thg = (const float*)d_in[17];
    const float* Wo  = (const float*)d_in[18];
    const float* bo  = (const float*)d_in[19];
    const float* Woq = (const float*)d_in[20];
    const float* boq = (const float*)d_in[21];
    const float* tho = (const float*)d_in[22];
    const float* Wq  = (const float*)d_in[23];
    const float* bq  = (const float*)d_in[24];

    float* ws = (float*)d_ws;
    float* Wxp    = ws;
    float* Whp    = Wxp + 528 * 128;
    float* bcatp  = Whp + 528 * 128;
    float* stateH = bcatp + NCPAD;
    float* stateC = stateH + 512 * 128;
    float* Zxb    = stateC + 512 * 128;

    size_t fixed_bytes = (size_t)(Zxb - ws) * sizeof(float);
    int TC = 256;
    while (TC > 4 && fixed_bytes + (size_t)TC * 512 * NCOL * 4 > ws_size) TC >>= 1;

    pack_weights<<<(NCOL * KK + 255) / 256, 256, 0, stream>>>(
        Wf, bf, Wfq, bfq, Wi, bi, Wiq, biq, Wg, bg, Wgq, bgq, Wo, bo, Woq, boq,
        Wxp, Whp, bcatp);

    for (int t0 = 0; t0 < TT; t0 += TC) {
        xgemm<<<dim3(TC * 512 / P1_BM, NCPAD / P1_BN), 256, 0, stream>>>(
            X + (size_t)t0 * BB * DD, Wxp, bcatp, Zxb);
        qlstm_rec<<<256, 1024, 0, stream>>>(
            Zxb, Whp, hx0, cx0, stateH, stateC, Wq, bq,
            thf, thi, thg, tho, (float*)d_out, t0, TC);
    }
}

// Round 4
// 1204.277 us; speedup vs baseline: 2.9893x; 1.1096x over previous
//
#include <hip/hip_runtime.h>
#include <cmath>

#define TT 256
#define BB 512
#define DD 128
#define HH 128
#define NCOL 528   // 4*H + 16 quantum-angle cols
#define KK 256
#define NCPAD 576  // 9 * 64

// ---------------- weight pack: Wxp[528][128], Whp[528][128], bcat[576] ----------------
__global__ __launch_bounds__(256) void pack_weights(
    const float* __restrict__ Wf, const float* __restrict__ bf,
    const float* __restrict__ Wfq, const float* __restrict__ bfq,
    const float* __restrict__ Wi, const float* __restrict__ bi,
    const float* __restrict__ Wiq, const float* __restrict__ biq,
    const float* __restrict__ Wg, const float* __restrict__ bg,
    const float* __restrict__ Wgq, const float* __restrict__ bgq,
    const float* __restrict__ Wo, const float* __restrict__ bo,
    const float* __restrict__ Woq, const float* __restrict__ boq,
    float* __restrict__ Wxp, float* __restrict__ Whp, float* __restrict__ bcat)
{
    int idx = blockIdx.x * blockDim.x + threadIdx.x;
    if (idx < NCOL * KK) {
        int c = idx >> 8, k = idx & 255;
        const float* srcW; int cl;
        if (c < 512) { int g = c >> 7; cl = c & 127;
            srcW = (g == 0) ? Wf : (g == 1) ? Wi : (g == 2) ? Wg : Wo; }
        else { int g = (c - 512) >> 2; cl = (c - 512) & 3;
            srcW = (g == 0) ? Wfq : (g == 1) ? Wiq : (g == 2) ? Wgq : Woq; }
        float v = srcW[(size_t)cl * KK + k];
        if (k < 128) Wxp[(size_t)c * 128 + k] = v;
        else         Whp[(size_t)c * 128 + (k - 128)] = v;
    }
    if (idx < NCPAD) {
        float b = 0.f;
        int c = idx;
        if (c < 512) { int g = c >> 7; int cl = c & 127;
            b = (g == 0) ? bf[cl] : (g == 1) ? bi[cl] : (g == 2) ? bg[cl] : bo[cl]; }
        else if (c < NCOL) { int g = (c - 512) >> 2; int cl = (c - 512) & 3;
            b = (g == 0) ? bfq[cl] : (g == 1) ? biq[cl] : (g == 2) ? bgq[cl] : boq[cl]; }
        bcat[c] = b;
    }
}

// ---------------- phase 1: Zx = X @ Wx^T + bcat  (M x 528, K=128) ----------------
#define P1_BM 128
#define P1_BN 64
__global__ __launch_bounds__(256, 3) void xgemm(
    const float* __restrict__ X, const float* __restrict__ Wxp,
    const float* __restrict__ bcat, float* __restrict__ Zx)
{
    __shared__ float At[64][P1_BM];
    __shared__ float Bt[64][P1_BN];
    const int tid = threadIdx.x;
    const int m0 = blockIdx.x * P1_BM;
    const int c0 = blockIdx.y * P1_BN;
    const int tm = tid >> 4;
    const int tn = tid & 15;
    float acc[8][4] = {};

    for (int khf = 0; khf < 2; ++khf) {
        #pragma unroll
        for (int j = 0; j < 8; ++j) {
            int fidx = tid + 256 * j;
            int m = fidx >> 4, k4 = (fidx & 15) * 4;
            float4 v = *(const float4*)(X + (size_t)(m0 + m) * 128 + khf * 64 + k4);
            At[k4 + 0][m] = v.x; At[k4 + 1][m] = v.y; At[k4 + 2][m] = v.z; At[k4 + 3][m] = v.w;
        }
        #pragma unroll
        for (int j = 0; j < 4; ++j) {
            int fidx = tid + 256 * j;
            int c = fidx >> 4, k4 = (fidx & 15) * 4;
            int cg = c0 + c;
            float4 v = make_float4(0.f, 0.f, 0.f, 0.f);
            if (cg < NCOL) v = *(const float4*)(Wxp + (size_t)cg * 128 + khf * 64 + k4);
            Bt[k4 + 0][c] = v.x; Bt[k4 + 1][c] = v.y; Bt[k4 + 2][c] = v.z; Bt[k4 + 3][c] = v.w;
        }
        __syncthreads();
        #pragma unroll 4
        for (int k = 0; k < 64; ++k) {
            float4 a0 = *(const float4*)&At[k][tm * 8];
            float4 a1 = *(const float4*)&At[k][tm * 8 + 4];
            float4 b  = *(const float4*)&Bt[k][tn * 4];
            float ar[8] = {a0.x, a0.y, a0.z, a0.w, a1.x, a1.y, a1.z, a1.w};
            float br[4] = {b.x, b.y, b.z, b.w};
            #pragma unroll
            for (int i = 0; i < 8; ++i)
                #pragma unroll
                for (int j = 0; j < 4; ++j)
                    acc[i][j] = fmaf(ar[i], br[j], acc[i][j]);
        }
        __syncthreads();
    }
    int c = c0 + tn * 4;
    if (c < NCOL) {
        float4 bias = *(const float4*)(bcat + c);
        #pragma unroll
        for (int i = 0; i < 8; ++i) {
            int m = m0 + tm * 8 + i;
            float4 o;
            o.x = acc[i][0] + bias.x; o.y = acc[i][1] + bias.y;
            o.z = acc[i][2] + bias.z; o.w = acc[i][3] + bias.w;
            *(float4*)(Zx + (size_t)m * NCOL + c) = o;
        }
    }
}

// ---------------- phase 2: recurrence ----------------
__device__ __forceinline__ float sigm(float x) { return 1.0f / (1.0f + __expf(-x)); }
__device__ __forceinline__ float tanh_f(float x) {
    float e = __expf(2.f * x);
    return 1.f - 2.f / (e + 1.f);
}

// NOTE: macro params must NOT be named x/y/z/w — they'd substitute into member access.
#define FMA4(acc, Wv, Xv) acc = fmaf((Wv).x, (Xv).x, fmaf((Wv).y, (Xv).y, fmaf((Wv).z, (Xv).z, fmaf((Wv).w, (Xv).w, (acc)))))
#define PIN4(Wv) asm volatile("" : "+v"((Wv).x), "+v"((Wv).y), "+v"((Wv).z), "+v"((Wv).w))

__global__ __launch_bounds__(1024, 4) void qlstm_rec(
    const float* __restrict__ Zx,      // [TC][512][528]
    const float* __restrict__ Whp,     // [528][128]
    const float* __restrict__ hx0, const float* __restrict__ cx0,
    float* __restrict__ stateH, float* __restrict__ stateC,
    const float* __restrict__ Wq, const float* __restrict__ bq,
    const float* __restrict__ thf, const float* __restrict__ thi,
    const float* __restrict__ thg, const float* __restrict__ tho,
    float* __restrict__ out, int t0, int TC)
{
    __shared__ __align__(16) float hL[2][HH];
    __shared__ float P[2][512][2];
    __shared__ float Pq[2][16][2];
    __shared__ float zqL[2][16];
    __shared__ float Whq[16][132];
    __shared__ float WqT[4][HH];
    __shared__ float bqL[HH];
    __shared__ float thL[4][4];   // [gate]{cos th0, cos th1, cos th2, th3}

    const int tid  = threadIdx.x;
    const int row0 = blockIdx.x * 2;
    const int col  = tid >> 1;       // 0..511
    const int kh   = tid & 1;        // k-half

    // Wh into registers: 16 named float4 (64 floats) per thread, pinned.
    const float4* wp = (const float4*)(Whp + ((size_t)col * 128 + (kh << 6)));
    float4 w00 = wp[0],  w01 = wp[1],  w02 = wp[2],  w03 = wp[3];
    float4 w04 = wp[4],  w05 = wp[5],  w06 = wp[6],  w07 = wp[7];
    float4 w08 = wp[8],  w09 = wp[9],  w10 = wp[10], w11 = wp[11];
    float4 w12 = wp[12], w13 = wp[13], w14 = wp[14], w15 = wp[15];
    PIN4(w00); PIN4(w01); PIN4(w02); PIN4(w03);
    PIN4(w04); PIN4(w05); PIN4(w06); PIN4(w07);
    PIN4(w08); PIN4(w09); PIN4(w10); PIN4(w11);
    PIN4(w12); PIN4(w13); PIN4(w14); PIN4(w15);

    if (tid < 512) {
        #pragma unroll
        for (int j = 0; j < 4; ++j) {
            int idx = tid * 4 + j;   // 0..2047 = 16 x 128
            Whq[idx >> 7][idx & 127] = Whp[(size_t)(512 + (idx >> 7)) * 128 + (idx & 127)];
        }
    }
    if (tid < HH) {
        bqL[tid] = bq[tid];
        WqT[0][tid] = Wq[tid * 4 + 0]; WqT[1][tid] = Wq[tid * 4 + 1];
        WqT[2][tid] = Wq[tid * 4 + 2]; WqT[3][tid] = Wq[tid * 4 + 3];
    }
    if (tid < 16) {
        int g = tid >> 2, w = tid & 3;
        const float* thp = (g == 0) ? thf : (g == 1) ? thi : (g == 2) ? thg : tho;
        thL[g][w] = (w == 3) ? thp[3] : cosf(thp[w]);
    }
    float cxr = 0.f;
    if (tid < 256) {
        int r = tid >> 7, h = tid & 127;
        const float* hs = (t0 == 0) ? hx0 : stateH;
        const float* cs = (t0 == 0) ? cx0 : stateC;
        hL[r][h] = hs[(size_t)(row0 + r) * HH + h];
        cxr      = cs[(size_t)(row0 + r) * HH + h];
    }
    __syncthreads();

    for (int tc = 0; tc < TC; ++tc) {
        const float* zrow = Zx + ((size_t)tc * BB + row0) * NCOL;
        // prefetch Zx (hidden under GEMM)
        float zc0 = 0, zc1 = 0, zc2 = 0, zc3 = 0;
        if (tid < 256) {
            int r = tid >> 7, h = tid & 127;
            const float* zp = zrow + (size_t)r * NCOL + h;
            zc0 = zp[0]; zc1 = zp[128]; zc2 = zp[256]; zc3 = zp[384];
        }
        float zqv = 0;
        if (tid < 32) zqv = zrow[(size_t)(tid >> 4) * NCOL + 512 + (tid & 15)];

        // ---- h-GEMM: (col, kh) partial dot, both rows ----
        {
            const float4* h0p = (const float4*)&hL[0][kh << 6];
            const float4* h1p = (const float4*)&hL[1][kh << 6];
            float s0a = 0, s0b = 0, s1a = 0, s1b = 0;
            #define GSTEP(J, WA, WB) { \
                float4 xa = h0p[J], xb = h0p[(J) + 1]; \
                float4 ya = h1p[J], yb = h1p[(J) + 1]; \
                FMA4(s0a, WA, xa); FMA4(s0b, WB, xb); \
                FMA4(s1a, WA, ya); FMA4(s1b, WB, yb); }
            GSTEP(0,  w00, w01) GSTEP(2,  w02, w03)
            GSTEP(4,  w04, w05) GSTEP(6,  w06, w07)
            GSTEP(8,  w08, w09) GSTEP(10, w10, w11)
            GSTEP(12, w12, w13) GSTEP(14, w14, w15)
            #undef GSTEP
            P[0][col][kh] = s0a + s0b;
            P[1][col][kh] = s1a + s1b;
        }
        // q-angle h-dots (LDS weights)
        if (tid < 64) {
            int qc = tid >> 2, k2 = (tid >> 1) & 1, r2 = tid & 1;
            const float* wq_ = &Whq[qc][k2 * 64];
            const float* hh  = &hL[r2][k2 * 64];
            float a = 0, b2 = 0;
            #pragma unroll
            for (int j = 0; j < 64; j += 2) { a = fmaf(wq_[j], hh[j], a); b2 = fmaf(wq_[j + 1], hh[j + 1], b2); }
            Pq[r2][qc][k2] = a + b2;
        }
        if (tid < 32) zqL[tid >> 4][tid & 15] = zqv;
        __syncthreads();

        // ---- cell update with closed-form quantum expectation ----
        if (tid < 256) {
            int r = tid >> 7, h = tid & 127;
            float2 pf2 = *(const float2*)&P[r][h][0];
            float2 pi2 = *(const float2*)&P[r][128 + h][0];
            float2 pg2 = *(const float2*)&P[r][256 + h][0];
            float2 po2 = *(const float2*)&P[r][384 + h][0];
            float pf = zc0 + pf2.x + pf2.y;
            float pi = zc1 + pi2.x + pi2.y;
            float pg = zc2 + pg2.x + pg2.y;
            float po = zc3 + po2.x + po2.y;
            float wq0 = WqT[0][h], wq1 = WqT[1][h], wq2 = WqT[2][h], wq3 = WqT[3][h];
            float bb = bqL[h];
            float qz[4];
            #pragma unroll
            for (int g = 0; g < 4; ++g) {
                float a0 = zqL[r][g * 4 + 0] + Pq[r][g * 4 + 0][0] + Pq[r][g * 4 + 0][1];
                float a1 = zqL[r][g * 4 + 1] + Pq[r][g * 4 + 1][0] + Pq[r][g * 4 + 1][1];
                float a2 = zqL[r][g * 4 + 2] + Pq[r][g * 4 + 2][0] + Pq[r][g * 4 + 2][1];
                float a3 = zqL[r][g * 4 + 3] + Pq[r][g * 4 + 3][0] + Pq[r][g * 4 + 3][1];
                float c0 = __cosf(a0), c1 = __cosf(a1), c2 = __cosf(a2);
                float c01  = c0 * c1;
                float c012 = c01 * c2;
                float e0 = thL[g][0] * c0;
                float e1 = thL[g][1] * c01;
                float e2 = thL[g][2] * c012;
                float e3 = c012 * __cosf(a3 + thL[g][3]);
                qz[g] = fmaf(e0, wq0, fmaf(e1, wq1, fmaf(e2, wq2, fmaf(e3, wq3, bb))));
            }
            float f  = sigm(pf)   + sigm(qz[0]);
            float ii = sigm(pi)   + sigm(qz[1]);
            float gg = tanh_f(pg) + tanh_f(qz[2]);
            float oo = sigm(po)   + sigm(qz[3]);
            float cn = fmaf(f, cxr, ii * gg);
            cxr = cn;
            float hn = oo * tanh_f(cn);
            hL[r][h] = hn;
            out[((size_t)(t0 + tc) * BB + row0 + r) * HH + h] = hn;
        }
        __syncthreads();
    }

    if (tid < 256) {
        int r = tid >> 7, h = tid & 127;
        stateH[(size_t)(row0 + r) * HH + h] = hL[r][h];
        stateC[(size_t)(row0 + r) * HH + h] = cxr;
        if (t0 + TC == TT) {
            size_t base = (size_t)TT * BB * HH;
            out[base + (size_t)(row0 + r) * HH + h]                   = hL[r][h];
            out[base + (size_t)BB * HH + (size_t)(row0 + r) * HH + h] = cxr;
        }
    }
}

extern "C" void kernel_launch(void* const* d_in, const int* in_sizes, int n_in,
                              void* d_out, int out_size, void* d_ws, size_t ws_size,
                              hipStream_t stream) {
    const float* X   = (const float*)d_in[0];
    const float* hx0 = (const float*)d_in[1];
    const float* cx0 = (const float*)d_in[2];
    const float* Wf  = (const float*)d_in[3];
    const float* bf  = (const float*)d_in[4];
    const float* Wfq = (const float*)d_in[5];
    const float* bfq = (const float*)d_in[6];
    const float* thf = (const float*)d_in[7];
    const float* Wi  = (const float*)d_in[8];
    const float* bi  = (const float*)d_in[9];
    const float* Wiq = (const float*)d_in[10];
    const float* biq = (const float*)d_in[11];
    const float* thi = (const float*)d_in[12];
    const float* Wg  = (const float*)d_in[13];
    const float* bg  = (const float*)d_in[14];
    const float* Wgq = (const float*)d_in[15];
    const float* bgq = (const float*)d_in[16];
    const float* thg = (const float*)d_in[17];
    const float* Wo  = (const float*)d_in[18];
    const float* bo  = (const float*)d_in[19];
    const float* Woq = (const float*)d_in[20];
    const float* boq = (const float*)d_in[21];
    const float* tho = (const float*)d_in[22];
    const float* Wq  = (const float*)d_in[23];
    const float* bq  = (const float*)d_in[24];

    float* ws = (float*)d_ws;
    float* Wxp    = ws;
    float* Whp    = Wxp + 528 * 128;
    float* bcatp  = Whp + 528 * 128;
    float* stateH = bcatp + NCPAD;
    float* stateC = stateH + 512 * 128;
    float* Zxb    = stateC + 512 * 128;

    size_t fixed_bytes = (size_t)(Zxb - ws) * sizeof(float);
    int TC = 256;
    while (TC > 4 && fixed_bytes + (size_t)TC * 512 * NCOL * 4 > ws_size) TC >>= 1;

    pack_weights<<<(NCOL * KK + 255) / 256, 256, 0, stream>>>(
        Wf, bf, Wfq, bfq, Wi, bi, Wiq, biq, Wg, bg, Wgq, bgq, Wo, bo, Woq, boq,
        Wxp, Whp, bcatp);

    for (int t0 = 0; t0 < TT; t0 += TC) {
        xgemm<<<dim3(TC * 512 / P1_BM, NCPAD / P1_BN), 256, 0, stream>>>(
            X + (size_t)t0 * BB * DD, Wxp, bcatp, Zxb);
        qlstm_rec<<<256, 1024, 0, stream>>>(
            Zxb, Whp, hx0, cx0, stateH, stateC, Wq, bq,
            thf, thi, thg, tho, (float*)d_out, t0, TC);
    }
}